// Round 6
// baseline (270.809 us; speedup 1.0000x reference)
//
#include <hip/hip_runtime.h>

#define NN 100000
#define NE 1250000
#define HD 64
#define BMW 3125         // bitmap words = NN/32
#define BMWPAD 3200      // padded for uint4 zeroing
#define GRID 256
#define TPB 512
#define NTH (GRID * TPB)     // 131072 threads
#define NWAVE (NTH / 64)     // 2048 waves

#define CAP_L3   4096
#define CAP_L2   65536
#define CAP_L1   262144
#define CAP_NL2  4096
#define CAP_NL1  65536
#define CAP_NL0  262144
#define S_N2CAP  128         // LDS slots for NL2 in k_tail (expected ~25)

// ctrl: 0=cntL3 1=cntL2 2=cntL1 3=cntNL2 4=cntNL1 5=cntNL0
// Bitmaps: B2 = NL2 (1-hop-from-pair srcs), B1 = NL1, B0 = NL0.

__device__ __forceinline__ unsigned ldg_u(const unsigned* p) {
    return __hip_atomic_load(p, __ATOMIC_RELAXED, __HIP_MEMORY_SCOPE_AGENT);
}
__device__ __forceinline__ int ldg_i(const int* p) {
    return __hip_atomic_load(p, __ATOMIC_RELAXED, __HIP_MEMORY_SCOPE_AGENT);
}
__device__ __forceinline__ float ldg_f(const float* p) {
    return __hip_atomic_load(p, __ATOMIC_RELAXED, __HIP_MEMORY_SCOPE_AGENT);
}
__device__ __forceinline__ void stg_i(int* p, int v) {
    __hip_atomic_store(p, v, __ATOMIC_RELAXED, __HIP_MEMORY_SCOPE_AGENT);
}
__device__ __forceinline__ void stg_f(float* p, float v) {
    __hip_atomic_store(p, v, __ATOMIC_RELAXED, __HIP_MEMORY_SCOPE_AGENT);
}

// Fence-free grid barrier (proven in R4): __syncthreads drains vmcnt before
// arrival; relaxed add + relaxed spin (no per-poll cache maintenance).
__device__ __forceinline__ void gbar(unsigned* cnt8, unsigned target) {
    __syncthreads();
    if (threadIdx.x == 0) {
        __hip_atomic_fetch_add(&cnt8[(blockIdx.x & 7u) * 16], 1u,
                               __ATOMIC_RELAXED, __HIP_MEMORY_SCOPE_AGENT);
        long guard = 0;
        for (;;) {
            unsigned s = 0;
#pragma unroll
            for (int i = 0; i < 8; ++i)
                s += __hip_atomic_load(&cnt8[i * 16], __ATOMIC_RELAXED,
                                       __HIP_MEMORY_SCOPE_AGENT);
            if (s >= target) break;
            __builtin_amdgcn_s_sleep(2);
            if (++guard > (1L << 24)) break;   // deadlock escape
        }
        asm volatile("" ::: "memory");
    }
    __syncthreads();
}

__global__ void k_pre(unsigned* B0, unsigned* B1, unsigned* B2,
                      unsigned* cnt8, int* ctrl, float* cnt_in,
                      const int* __restrict__ pair) {
    int i = blockIdx.x * blockDim.x + threadIdx.x;
    uint4 zz = make_uint4(0u, 0u, 0u, 0u);
    for (int t = i; t < 3 * BMWPAD / 4; t += gridDim.x * blockDim.x) {
        if (t < BMWPAD / 4)           ((uint4*)B0)[t] = zz;
        else if (t < 2 * BMWPAD / 4)  ((uint4*)B1)[t - BMWPAD / 4] = zz;
        else                          ((uint4*)B2)[t - 2 * BMWPAD / 4] = zz;
    }
    if (i < 128) cnt8[i] = 0u;
    if (i < 16)  ctrl[i] = 0;
    if (i == 0) { cnt_in[pair[0]] = 0.f; cnt_in[pair[1]] = 0.f; }
}

__global__ __launch_bounds__(TPB) void k_mega(
        const int* __restrict__ z, const int* __restrict__ src,
        const int* __restrict__ dst, const int* __restrict__ pair,
        const float* __restrict__ zt,
        float* bufA, float* bufB, float* cnt_out, float* cnt_in,
        unsigned* B0, unsigned* B1, unsigned* B2,
        int* L3, int* L2, int* L1, int* NL2, int* NL1, int* NL0,
        int* ctrl, unsigned* cnt8) {
    __shared__ unsigned bm[BMW];
    __shared__ int cnts[8];
    const int tid  = threadIdx.x;
    const int gtid = blockIdx.x * TPB + tid;
    const int gw   = gtid >> 6, lane = gtid & 63;
    const int p0 = pair[0], p1 = pair[1];

    // ---- P1: scan3 — edges into {pair}; mark NL2 in B2 ----
    for (int t = gtid; t < NE / 4; t += NTH) {
        int4 d4 = ((const int4*)dst)[t];
#pragma unroll
        for (int k = 0; k < 4; ++k) {
            int d = (k == 0) ? d4.x : (k == 1) ? d4.y : (k == 2) ? d4.z : d4.w;
            if (d == p0 || d == p1) {
                int e = t * 4 + k, s = src[e];
                int idx = atomicAdd(&ctrl[0], 1);
                if (idx < CAP_L3) stg_i(&L3[idx], e);
                unsigned m = 1u << (s & 31);
                unsigned old = atomicOr(&B2[s >> 5], m);
                if (!(old & m)) {
                    stg_f(&cnt_out[s], 0.f); stg_f(&cnt_in[s], 0.f);
                    int j = atomicAdd(&ctrl[3], 1);
                    if (j < CAP_NL2) stg_i(&NL2[j], s);
                }
            }
        }
    }
    gbar(cnt8, 1u * GRID);

    // ---- P2: scan2 — dst in B2 (LDS-staged); mark NL1 in B1 ----
    for (int i = tid; i < BMW; i += TPB) bm[i] = ldg_u(&B2[i]);
    __syncthreads();
    for (int t = gtid; t < NE / 4; t += NTH) {
        int4 d4 = ((const int4*)dst)[t];
#pragma unroll
        for (int k = 0; k < 4; ++k) {
            int d = (k == 0) ? d4.x : (k == 1) ? d4.y : (k == 2) ? d4.z : d4.w;
            if ((bm[d >> 5] >> (d & 31)) & 1u) {
                int e = t * 4 + k, s = src[e];
                int idx = atomicAdd(&ctrl[1], 1);
                if (idx < CAP_L2) stg_i(&L2[idx], e);
                unsigned m = 1u << (s & 31);
                unsigned old = atomicOr(&B1[s >> 5], m);
                if (!(old & m)) {
                    stg_f(&cnt_out[s], 0.f); stg_f(&cnt_in[s], 0.f);
                    int j = atomicAdd(&ctrl[4], 1);
                    if (j < CAP_NL1) stg_i(&NL1[j], s);
                }
            }
        }
    }
    gbar(cnt8, 2u * GRID);

    // ---- P3: scan1 — dst in B1; mark NL0 in B0 ----
    for (int i = tid; i < BMW; i += TPB) bm[i] = ldg_u(&B1[i]);
    __syncthreads();
    for (int t = gtid; t < NE / 4; t += NTH) {
        int4 d4 = ((const int4*)dst)[t];
#pragma unroll
        for (int k = 0; k < 4; ++k) {
            int d = (k == 0) ? d4.x : (k == 1) ? d4.y : (k == 2) ? d4.z : d4.w;
            if ((bm[d >> 5] >> (d & 31)) & 1u) {
                int e = t * 4 + k, s = src[e];
                int idx = atomicAdd(&ctrl[2], 1);
                if (idx < CAP_L1) stg_i(&L1[idx], e);
                unsigned m = 1u << (s & 31);
                unsigned old = atomicOr(&B0[s >> 5], m);
                if (!(old & m)) {
                    stg_f(&cnt_out[s], 0.f);
                    int j = atomicAdd(&ctrl[5], 1);
                    if (j < CAP_NL0) stg_i(&NL0[j], s);
                }
            }
        }
    }
    gbar(cnt8, 3u * GRID);

    if (tid < 6) cnts[tid] = ldg_i(&ctrl[tid]);
    __syncthreads();
    const int e3 = min(cnts[0], CAP_L3), e2 = min(cnts[1], CAP_L2), e1 = min(cnts[2], CAP_L1);
    const int n1 = min(cnts[4], CAP_NL1), n0 = min(cnts[5], CAP_NL0);

    // ---- P4: out-deg over union bitmap; deduped in-deg; x0 gather + agg1 zero ----
    for (int i = tid; i < BMW; i += TPB) bm[i] = ldg_u(&B0[i]) | ldg_u(&B1[i]) | ldg_u(&B2[i]);
    __syncthreads();
    for (int t = gtid; t < NE / 4; t += NTH) {
        int4 s4 = ((const int4*)src)[t];
#pragma unroll
        for (int k = 0; k < 4; ++k) {
            int s = (k == 0) ? s4.x : (k == 1) ? s4.y : (k == 2) ? s4.z : s4.w;
            if ((bm[s >> 5] >> (s & 31)) & 1u) atomicAdd(&cnt_out[s], 1.0f);
        }
    }
    // in-degree: count each dst from its highest-priority list only (B1 > B2 > pair)
    for (int t = gtid; t < e1 + e2 + e3; t += NTH) {
        int e, which;
        if (t < e1)            { e = ldg_i(&L1[t]);           which = 1; }
        else if (t < e1 + e2)  { e = ldg_i(&L2[t - e1]);      which = 2; }
        else                   { e = ldg_i(&L3[t - e1 - e2]); which = 3; }
        int d = dst[e];
        bool inB1 = (ldg_u(&B1[d >> 5]) >> (d & 31)) & 1u;
        bool count;
        if (which == 1)      count = true;
        else if (which == 2) count = !inB1;
        else                 count = !inB1 && !((ldg_u(&B2[d >> 5]) >> (d & 31)) & 1u);
        if (count) atomicAdd(&cnt_in[d], 1.0f);
    }
    // prep: x0 rows for NL0 into bufA; zero agg1 rows (NL1) in bufB
    for (int r = gw; r < n0 + n1; r += NWAVE) {
        if (r < n0) {
            int v = ldg_i(&NL0[r]);
            stg_f(&bufA[v * HD + lane], zt[z[v] * HD + lane]);
        } else {
            int v = ldg_i(&NL1[r - n0]);
            stg_f(&bufB[v * HD + lane], 0.0f);
        }
    }
    gbar(cnt8, 4u * GRID);

    // ---- P5: scatter layer 1 (x0 in bufA -> agg1 in bufB); kernel end = sync ----
    for (int r = gw; r < e1; r += NWAVE) {
        int e = ldg_i(&L1[r]), s = src[e], d = dst[e];
        float w0 = 1.0f / sqrtf(fmaxf(ldg_f(&cnt_out[s]), 1.0f));
        atomicAdd(&bufB[d * HD + lane], w0 * ldg_f(&bufA[s * HD + lane]));
    }
}

// Single-block tail: gemm1, scatter2(LDS), gemm2(LDS), scatter3(LDS), gemm3, MLP.
__global__ __launch_bounds__(1024) void k_tail(
        const int* __restrict__ src, const int* __restrict__ dst,
        const int* __restrict__ pair,
        const float* __restrict__ W1, const float* __restrict__ b1,
        const float* __restrict__ W2, const float* __restrict__ b2,
        const float* __restrict__ W3, const float* __restrict__ b3,
        const float* __restrict__ l1w, const float* __restrict__ l1b,
        const float* __restrict__ l2w, const float* __restrict__ l2b,
        float* out,
        float* bufB, const float* __restrict__ cnt_out,
        const float* __restrict__ cnt_in,
        const int* __restrict__ L3, const int* __restrict__ L2,
        const int* __restrict__ NL2, const int* __restrict__ NL1,
        const int* __restrict__ ctrl) {
    __shared__ float x2agg[S_N2CAP * HD];   // 32 KB: agg2 then x2, by NL2 slot
    __shared__ int   s_nl2[S_N2CAP];
    __shared__ float xs[2 * HD], xf[2 * HD];
    __shared__ int cnts[8];
    const int tid = threadIdx.x;
    const int wv = tid >> 6, ln = tid & 63;   // 16 waves
    const int p0 = pair[0], p1 = pair[1];

    if (tid < 6) cnts[tid] = ctrl[tid];
    __syncthreads();
    const int e3 = min(cnts[0], CAP_L3), e2 = min(cnts[1], CAP_L2);
    const int n2 = min(min(cnts[3], CAP_NL2), S_N2CAP);
    const int n1 = min(cnts[4], CAP_NL1);

    // stage NL2 slots + zero agg2 + zero xs
    for (int i = tid; i < S_N2CAP * HD; i += 1024) x2agg[i] = 0.0f;
    if (tid < n2) s_nl2[tid] = NL2[tid];
    if (tid < 2 * HD) xs[tid] = 0.0f;

    // gemm1: x1 = relu((agg1 * nin) @ W1 + b1), wave per row (no LDS deps yet)
    for (int r = wv; r < n1; r += 16) {
        int v = NL1[r];
        float nin = 1.0f / sqrtf(fmaxf(cnt_in[v], 1.0f));
        float a = bufB[v * HD + ln] * nin;
        float acc = b1[ln];
#pragma unroll
        for (int i = 0; i < HD; ++i)
            acc += __shfl(a, i, 64) * W1[i * HD + ln];
        bufB[v * HD + ln] = fmaxf(acc, 0.0f);
    }
    __syncthreads();

    // scatter2: agg2[slot(d)] += w0 * x1[s], item = (edge, 4-col chunk)
    for (int it = tid; it < e2 * 16; it += 1024) {
        int e = L2[it >> 4], col = (it & 15) * 4;
        int s = src[e], d = dst[e];
        float w0 = 1.0f / sqrtf(fmaxf(cnt_out[s], 1.0f));
        int slot = 0;
        for (int j = 0; j < n2; ++j) if (s_nl2[j] == d) { slot = j; break; }
        float4 v4 = *(const float4*)&bufB[s * HD + col];
        atomicAdd(&x2agg[slot * HD + col + 0], w0 * v4.x);
        atomicAdd(&x2agg[slot * HD + col + 1], w0 * v4.y);
        atomicAdd(&x2agg[slot * HD + col + 2], w0 * v4.z);
        atomicAdd(&x2agg[slot * HD + col + 3], w0 * v4.w);
    }
    __syncthreads();

    // gemm2 in-place in LDS: x2 = relu((agg2 * nin) @ W2 + b2)
    for (int r = wv; r < n2; r += 16) {
        int v = s_nl2[r];
        float nin = 1.0f / sqrtf(fmaxf(cnt_in[v], 1.0f));
        float a = x2agg[r * HD + ln] * nin;
        float acc = b2[ln];
#pragma unroll
        for (int i = 0; i < HD; ++i)
            acc += __shfl(a, i, 64) * W2[i * HD + ln];
        x2agg[r * HD + ln] = fmaxf(acc, 0.0f);
    }
    __syncthreads();

    // scatter3: xs[{p0,p1} rows] += w0 * x2[slot(s)], wave per edge
    for (int r = wv; r < e3; r += 16) {
        int e = L3[r], s = src[e], d = dst[e];
        float w0 = 1.0f / sqrtf(fmaxf(cnt_out[s], 1.0f));
        int slot = 0;
        for (int j = 0; j < n2; ++j) if (s_nl2[j] == s) { slot = j; break; }
        float c = w0 * x2agg[slot * HD + ln];
        if (d == p0)             atomicAdd(&xs[ln], c);
        if (d == p1 && p1 != p0) atomicAdd(&xs[HD + ln], c);
    }
    __syncthreads();

    // gemm3 (no relu) on the two pair rows
    if (tid < 128) {
        int pv = wv ? p1 : p0;
        int rsrc = (wv && p1 != p0) ? 1 : 0;
        float nin = 1.0f / sqrtf(fmaxf(cnt_in[pv], 1.0f));
        float a = xs[rsrc * HD + ln] * nin;
        float acc = b3[ln];
#pragma unroll
        for (int i = 0; i < HD; ++i)
            acc += __shfl(a, i, 64) * W3[i * HD + ln];
        xf[wv * HD + ln] = acc;
    }
    __syncthreads();

    // final MLP
    if (tid < 64) {
        float h = xf[tid] * xf[HD + tid];
        float t2 = l1b[tid];
#pragma unroll
        for (int i = 0; i < HD; ++i)
            t2 += __shfl(h, i, 64) * l1w[i * HD + tid];
        t2 = fmaxf(t2, 0.0f);
        float val = t2 * l2w[tid];
#pragma unroll
        for (int off = 32; off; off >>= 1)
            val += __shfl_down(val, off, 64);
        if (tid == 0) out[0] = val + l2b[0];
    }
}

extern "C" void kernel_launch(void* const* d_in, const int* in_sizes, int n_in,
                              void* d_out, int out_size, void* d_ws, size_t ws_size,
                              hipStream_t stream) {
    const int*   z    = (const int*)d_in[0];
    const int*   src  = (const int*)d_in[1];
    const int*   dst  = (const int*)d_in[2];
    const int*   pair = (const int*)d_in[3];
    const float* zt   = (const float*)d_in[4];
    const float* W1   = (const float*)d_in[5];
    const float* b1   = (const float*)d_in[6];
    const float* W2   = (const float*)d_in[7];
    const float* b2   = (const float*)d_in[8];
    const float* W3   = (const float*)d_in[9];
    const float* b3   = (const float*)d_in[10];
    const float* l1w  = (const float*)d_in[11];
    const float* l1b  = (const float*)d_in[12];
    const float* l2w  = (const float*)d_in[13];
    const float* l2b  = (const float*)d_in[14];
    float* out = (float*)d_out;

    char* w = (char*)d_ws;
    auto alloc = [&](size_t bytes) {
        char* p = w;
        w += (bytes + 255) & ~(size_t)255;
        return p;
    };
    float*    bufA    = (float*)alloc((size_t)NN * HD * 4);
    float*    bufB    = (float*)alloc((size_t)NN * HD * 4);
    float*    cnt_out = (float*)alloc((size_t)NN * 4);
    float*    cnt_in  = (float*)alloc((size_t)NN * 4);
    unsigned* B0      = (unsigned*)alloc((size_t)BMWPAD * 4);
    unsigned* B1      = (unsigned*)alloc((size_t)BMWPAD * 4);
    unsigned* B2      = (unsigned*)alloc((size_t)BMWPAD * 4);
    int*      L3      = (int*)alloc((size_t)CAP_L3 * 4);
    int*      L2      = (int*)alloc((size_t)CAP_L2 * 4);
    int*      L1      = (int*)alloc((size_t)CAP_L1 * 4);
    int*      NL2     = (int*)alloc((size_t)CAP_NL2 * 4);
    int*      NL1     = (int*)alloc((size_t)CAP_NL1 * 4);
    int*      NL0     = (int*)alloc((size_t)CAP_NL0 * 4);
    int*      ctrl    = (int*)alloc(256);
    unsigned* cnt8    = (unsigned*)alloc(512);

    k_pre<<<8, 256, 0, stream>>>(B0, B1, B2, cnt8, ctrl, cnt_in, pair);
    k_mega<<<GRID, TPB, 0, stream>>>(z, src, dst, pair, zt,
                                     bufA, bufB, cnt_out, cnt_in,
                                     B0, B1, B2, L3, L2, L1, NL2, NL1, NL0,
                                     ctrl, cnt8);
    k_tail<<<1, 1024, 0, stream>>>(src, dst, pair,
                                   W1, b1, W2, b2, W3, b3,
                                   l1w, l1b, l2w, l2b, out,
                                   bufB, cnt_out, cnt_in,
                                   L3, L2, NL2, NL1, ctrl);
}

// Round 7
// 112.166 us; speedup vs baseline: 2.4144x; 2.4144x over previous
//
#include <hip/hip_runtime.h>

#define NN 100000
#define NE 1250000
#define HD 64
#define BMW 3125         // bitmap words = NN/32
#define BMWPAD 3200      // padded for uint4 zeroing
#define NBE4 1221        // ceil((NE/4)/256)

#define CAP_L3   4096
#define CAP_L2   65536
#define CAP_L1   262144
#define CAP_NL2  4096
#define CAP_NL1  65536

// ctrl: 0=cntL3 1=cntL2 2=cntL1 3=cntNL2 4=cntNL1
// Bitmaps: B2 = NL2 (in-nbrs of pair), B1 = NL1, B0 = frontier-0 (no list kept).

__global__ void k_init(unsigned* B0, unsigned* B1, unsigned* B2,
                       int* ctrl, float* cnt_in, const int* __restrict__ pair) {
    int i = blockIdx.x * blockDim.x + threadIdx.x;
    uint4 zz = make_uint4(0u, 0u, 0u, 0u);
    for (int t = i; t < 3 * BMWPAD / 4; t += gridDim.x * blockDim.x) {
        if (t < BMWPAD / 4)           ((uint4*)B0)[t] = zz;
        else if (t < 2 * BMWPAD / 4)  ((uint4*)B1)[t - BMWPAD / 4] = zz;
        else                          ((uint4*)B2)[t - 2 * BMWPAD / 4] = zz;
    }
    if (i < 16) ctrl[i] = 0;
    if (i == 0) { cnt_in[pair[0]] = 0.f; cnt_in[pair[1]] = 0.f; }
}

// sweep 1: edges into {pair}; mark srcs in B2, append NL2, lazy-zero counters
__global__ __launch_bounds__(256) void k_scan3(
        const int* __restrict__ src, const int* __restrict__ dst,
        const int* __restrict__ pair, unsigned* B2,
        float* cnt_out, float* cnt_in, int* L3, int* NL2, int* ctrl) {
    int t = blockIdx.x * blockDim.x + threadIdx.x;
    if (t >= NE / 4) return;
    int p0 = pair[0], p1 = pair[1];
    int4 d4 = ((const int4*)dst)[t];
#pragma unroll
    for (int k = 0; k < 4; ++k) {
        int d = (k == 0) ? d4.x : (k == 1) ? d4.y : (k == 2) ? d4.z : d4.w;
        if (d == p0 || d == p1) {
            int e = t * 4 + k, s = src[e];
            int idx = atomicAdd(&ctrl[0], 1);
            if (idx < CAP_L3) L3[idx] = e;
            unsigned m = 1u << (s & 31);
            unsigned old = atomicOr(&B2[s >> 5], m);
            if (!(old & m)) {
                cnt_out[s] = 0.f; cnt_in[s] = 0.f;
                int j = atomicAdd(&ctrl[3], 1);
                if (j < CAP_NL2) NL2[j] = s;
            }
        }
    }
}

// generic sweep: collect edges with dst-bit in testbm (L1-resident, 12.5KB);
// first-set src bit in setbm, lazy-zero counters, optionally append NL.
__global__ __launch_bounds__(256) void k_scan(
        const int* __restrict__ src, const int* __restrict__ dst,
        const unsigned* __restrict__ testbm, unsigned* setbm,
        float* cz_out, float* cz_in,
        int* L, int cntL_idx, int capL,
        int* NL, int cntNL_idx, int capNL, int* ctrl) {
    int t = blockIdx.x * blockDim.x + threadIdx.x;
    if (t >= NE / 4) return;
    int4 d4 = ((const int4*)dst)[t];
#pragma unroll
    for (int k = 0; k < 4; ++k) {
        int d = (k == 0) ? d4.x : (k == 1) ? d4.y : (k == 2) ? d4.z : d4.w;
        if ((testbm[d >> 5] >> (d & 31)) & 1u) {
            int e = t * 4 + k, s = src[e];
            int idx = atomicAdd(&ctrl[cntL_idx], 1);
            if (idx < capL) L[idx] = e;
            unsigned m = 1u << (s & 31);
            unsigned old = atomicOr(&setbm[s >> 5], m);
            if (!(old & m)) {
                cz_out[s] = 0.f;
                if (cz_in) cz_in[s] = 0.f;
                if (NL) {
                    int j = atomicAdd(&ctrl[cntNL_idx], 1);
                    if (j < capNL) NL[j] = s;
                }
            }
        }
    }
}

// fused: [0,NBE4) out-deg sweep | [NBE4,+32) deduped in-deg | rest: zero agg1 rows
__global__ __launch_bounds__(256) void k_mid(
        const int* __restrict__ src, const int* __restrict__ dst,
        const unsigned* __restrict__ B0, const unsigned* __restrict__ B1,
        const unsigned* __restrict__ B2,
        float* cnt_out, float* cnt_in, float* bufB,
        const int* __restrict__ L3, const int* __restrict__ L2,
        const int* __restrict__ L1, const int* __restrict__ NL1,
        const int* __restrict__ ctrl) {
    int b = blockIdx.x, tid = threadIdx.x;
    if (b < NBE4) {
        int t = b * 256 + tid;
        if (t >= NE / 4) return;
        int4 s4 = ((const int4*)src)[t];
#pragma unroll
        for (int k = 0; k < 4; ++k) {
            int s = (k == 0) ? s4.x : (k == 1) ? s4.y : (k == 2) ? s4.z : s4.w;
            unsigned w = B0[s >> 5] | B1[s >> 5] | B2[s >> 5];
            if ((w >> (s & 31)) & 1u) atomicAdd(&cnt_out[s], 1.0f);
        }
    } else if (b < NBE4 + 32) {
        int e3 = min(ctrl[0], CAP_L3), e2 = min(ctrl[1], CAP_L2), e1 = min(ctrl[2], CAP_L1);
        for (int t = (b - NBE4) * 256 + tid; t < e1 + e2 + e3; t += 32 * 256) {
            int e, which;
            if (t < e1)            { e = L1[t];           which = 1; }
            else if (t < e1 + e2)  { e = L2[t - e1];      which = 2; }
            else                   { e = L3[t - e1 - e2]; which = 3; }
            int d = dst[e];
            bool inB1 = (B1[d >> 5] >> (d & 31)) & 1u;
            bool count;
            if (which == 1)      count = true;
            else if (which == 2) count = !inB1;
            else                 count = !inB1 && !((B2[d >> 5] >> (d & 31)) & 1u);
            if (count) atomicAdd(&cnt_in[d], 1.0f);
        }
    } else {
        int n1 = min(ctrl[4], CAP_NL1);
        int nb = gridDim.x - NBE4 - 32;
        float4 zz = make_float4(0.f, 0.f, 0.f, 0.f);
        for (int t = (b - NBE4 - 32) * 256 + tid; t < n1 * 16; t += nb * 256) {
            int v = NL1[t >> 4], c = (t & 15) * 4;
            *(float4*)&bufB[v * HD + c] = zz;
        }
    }
}

// scatter layer 1: agg1[d] += w0(s) * zt[z[s]]   (x0 read fused, no staging)
__global__ __launch_bounds__(256) void k_scatter1(
        const int* __restrict__ L1, const int* __restrict__ ctrl,
        const int* __restrict__ src, const int* __restrict__ dst,
        const int* __restrict__ z, const float* __restrict__ zt,
        const float* __restrict__ cnt_out, float* bufB) {
    int e1 = min(ctrl[2], CAP_L1);
    int gtid = blockIdx.x * blockDim.x + threadIdx.x;
    int gw = gtid >> 6, lane = gtid & 63;
    int nw = (gridDim.x * blockDim.x) >> 6;
    for (int r = gw; r < e1; r += nw) {
        int e = L1[r], s = src[e], d = dst[e];
        float w0 = 1.0f / sqrtf(fmaxf(cnt_out[s], 1.0f));
        atomicAdd(&bufB[d * HD + lane], w0 * zt[z[s] * HD + lane]);
    }
}

// gemm1 (x1 = relu((agg1*nin)@W1+b1)) on NL1 rows of bufB; plus zero NL2 rows of bufA
__global__ __launch_bounds__(256) void k_gemm1z(
        const int* __restrict__ NL1, const int* __restrict__ NL2,
        const int* __restrict__ ctrl, const float* __restrict__ cnt_in,
        float* bufB, float* bufA,
        const float* __restrict__ W1, const float* __restrict__ b1) {
    int n1 = min(ctrl[4], CAP_NL1), n2 = min(ctrl[3], CAP_NL2);
    int gtid = blockIdx.x * blockDim.x + threadIdx.x;
    int gw = gtid >> 6, lane = gtid & 63;
    int nw = (gridDim.x * blockDim.x) >> 6;
    float wb = b1[lane];
    for (int r = gw; r < n1 + n2; r += nw) {
        if (r < n1) {
            int v = NL1[r];
            float nin = 1.0f / sqrtf(fmaxf(cnt_in[v], 1.0f));
            float a = bufB[v * HD + lane] * nin;
            float acc = wb;
#pragma unroll
            for (int i = 0; i < HD; ++i)
                acc += __shfl(a, i, 64) * W1[i * HD + lane];
            bufB[v * HD + lane] = fmaxf(acc, 0.0f);
        } else {
            int v = NL2[r - n1];
            bufA[v * HD + lane] = 0.0f;
        }
    }
}

// scatter layer 2: agg2[d] += w0(s) * x1[s]
__global__ __launch_bounds__(256) void k_scatter2(
        const int* __restrict__ L2, const int* __restrict__ ctrl,
        const int* __restrict__ src, const int* __restrict__ dst,
        const float* __restrict__ cnt_out,
        const float* __restrict__ bufB, float* bufA) {
    int e2 = min(ctrl[1], CAP_L2);
    int gtid = blockIdx.x * blockDim.x + threadIdx.x;
    int gw = gtid >> 6, lane = gtid & 63;
    int nw = (gridDim.x * blockDim.x) >> 6;
    for (int r = gw; r < e2; r += nw) {
        int e = L2[r], s = src[e], d = dst[e];
        float w0 = 1.0f / sqrtf(fmaxf(cnt_out[s], 1.0f));
        atomicAdd(&bufA[d * HD + lane], w0 * bufB[s * HD + lane]);
    }
}

// gemm2 (x2 = relu((agg2*nin)@W2+b2)) on NL2 rows of bufA
__global__ __launch_bounds__(256) void k_gemm2(
        const int* __restrict__ NL2, const int* __restrict__ ctrl,
        const float* __restrict__ cnt_in, float* bufA,
        const float* __restrict__ W2, const float* __restrict__ b2) {
    int n2 = min(ctrl[3], CAP_NL2);
    int gtid = blockIdx.x * blockDim.x + threadIdx.x;
    int gw = gtid >> 6, lane = gtid & 63;
    int nw = (gridDim.x * blockDim.x) >> 6;
    float wb = b2[lane];
    for (int r = gw; r < n2; r += nw) {
        int v = NL2[r];
        float nin = 1.0f / sqrtf(fmaxf(cnt_in[v], 1.0f));
        float a = bufA[v * HD + lane] * nin;
        float acc = wb;
#pragma unroll
        for (int i = 0; i < HD; ++i)
            acc += __shfl(a, i, 64) * W2[i * HD + lane];
        bufA[v * HD + lane] = fmaxf(acc, 0.0f);
    }
}

// single block: scatter3 (LDS), gemm3 (no relu), final MLP
__global__ __launch_bounds__(256) void k_last(
        const int* __restrict__ src, const int* __restrict__ dst,
        const int* __restrict__ pair, const int* __restrict__ L3,
        const int* __restrict__ ctrl,
        const float* __restrict__ cnt_out, const float* __restrict__ cnt_in,
        const float* __restrict__ bufA,
        const float* __restrict__ W3, const float* __restrict__ b3,
        const float* __restrict__ l1w, const float* __restrict__ l1b,
        const float* __restrict__ l2w, const float* __restrict__ l2b,
        float* out) {
    __shared__ float xs[2 * HD], xf[2 * HD];
    const int tid = threadIdx.x;
    const int wv = tid >> 6, ln = tid & 63;   // 4 waves
    const int p0 = pair[0], p1 = pair[1];
    const int e3 = min(ctrl[0], CAP_L3);

    if (tid < 2 * HD) xs[tid] = 0.0f;
    __syncthreads();
    for (int r = wv; r < e3; r += 4) {
        int e = L3[r], s = src[e], d = dst[e];
        float w0 = 1.0f / sqrtf(fmaxf(cnt_out[s], 1.0f));
        float c = w0 * bufA[s * HD + ln];
        if (d == p0)             atomicAdd(&xs[ln], c);
        if (d == p1 && p1 != p0) atomicAdd(&xs[HD + ln], c);
    }
    __syncthreads();
    if (tid < 128) {
        int pv = wv ? p1 : p0;
        int rsrc = (wv && p1 != p0) ? 1 : 0;   // p0==p1: both use row 0
        float nin = 1.0f / sqrtf(fmaxf(cnt_in[pv], 1.0f));
        float a = xs[rsrc * HD + ln] * nin;
        float acc = b3[ln];
#pragma unroll
        for (int i = 0; i < HD; ++i)
            acc += __shfl(a, i, 64) * W3[i * HD + ln];
        xf[wv * HD + ln] = acc;
    }
    __syncthreads();
    if (tid < 64) {
        float h = xf[tid] * xf[HD + tid];
        float t2 = l1b[tid];
#pragma unroll
        for (int i = 0; i < HD; ++i)
            t2 += __shfl(h, i, 64) * l1w[i * HD + tid];
        t2 = fmaxf(t2, 0.0f);
        float val = t2 * l2w[tid];
#pragma unroll
        for (int off = 32; off; off >>= 1)
            val += __shfl_down(val, off, 64);
        if (tid == 0) out[0] = val + l2b[0];
    }
}

extern "C" void kernel_launch(void* const* d_in, const int* in_sizes, int n_in,
                              void* d_out, int out_size, void* d_ws, size_t ws_size,
                              hipStream_t stream) {
    const int*   z    = (const int*)d_in[0];
    const int*   src  = (const int*)d_in[1];
    const int*   dst  = (const int*)d_in[2];
    const int*   pair = (const int*)d_in[3];
    const float* zt   = (const float*)d_in[4];
    const float* W1   = (const float*)d_in[5];
    const float* b1   = (const float*)d_in[6];
    const float* W2   = (const float*)d_in[7];
    const float* b2   = (const float*)d_in[8];
    const float* W3   = (const float*)d_in[9];
    const float* b3   = (const float*)d_in[10];
    const float* l1w  = (const float*)d_in[11];
    const float* l1b  = (const float*)d_in[12];
    const float* l2w  = (const float*)d_in[13];
    const float* l2b  = (const float*)d_in[14];
    float* out = (float*)d_out;

    char* w = (char*)d_ws;
    auto alloc = [&](size_t bytes) {
        char* p = w;
        w += (bytes + 255) & ~(size_t)255;
        return p;
    };
    float*    bufA    = (float*)alloc((size_t)NN * HD * 4);
    float*    bufB    = (float*)alloc((size_t)NN * HD * 4);
    float*    cnt_out = (float*)alloc((size_t)NN * 4);
    float*    cnt_in  = (float*)alloc((size_t)NN * 4);
    unsigned* B0      = (unsigned*)alloc((size_t)BMWPAD * 4);
    unsigned* B1      = (unsigned*)alloc((size_t)BMWPAD * 4);
    unsigned* B2      = (unsigned*)alloc((size_t)BMWPAD * 4);
    int*      L3      = (int*)alloc((size_t)CAP_L3 * 4);
    int*      L2      = (int*)alloc((size_t)CAP_L2 * 4);
    int*      L1      = (int*)alloc((size_t)CAP_L1 * 4);
    int*      NL2     = (int*)alloc((size_t)CAP_NL2 * 4);
    int*      NL1     = (int*)alloc((size_t)CAP_NL1 * 4);
    int*      ctrl    = (int*)alloc(256);

    dim3 b(256);

    k_init<<<16, b, 0, stream>>>(B0, B1, B2, ctrl, cnt_in, pair);
    k_scan3<<<NBE4, b, 0, stream>>>(src, dst, pair, B2, cnt_out, cnt_in, L3, NL2, ctrl);
    k_scan<<<NBE4, b, 0, stream>>>(src, dst, B2, B1, cnt_out, cnt_in,
                                   L2, 1, CAP_L2, NL1, 4, CAP_NL1, ctrl);
    k_scan<<<NBE4, b, 0, stream>>>(src, dst, B1, B0, cnt_out, (float*)nullptr,
                                   L1, 2, CAP_L1, (int*)nullptr, 0, 0, ctrl);
    k_mid<<<NBE4 + 32 + 96, b, 0, stream>>>(src, dst, B0, B1, B2,
                                            cnt_out, cnt_in, bufB,
                                            L3, L2, L1, NL1, ctrl);
    k_scatter1<<<512, b, 0, stream>>>(L1, ctrl, src, dst, z, zt, cnt_out, bufB);
    k_gemm1z<<<256, b, 0, stream>>>(NL1, NL2, ctrl, cnt_in, bufB, bufA, W1, b1);
    k_scatter2<<<64, b, 0, stream>>>(L2, ctrl, src, dst, cnt_out, bufB, bufA);
    k_gemm2<<<16, b, 0, stream>>>(NL2, ctrl, cnt_in, bufA, W2, b2);
    k_last<<<1, b, 0, stream>>>(src, dst, pair, L3, ctrl, cnt_out, cnt_in,
                                bufA, W3, b3, l1w, l1b, l2w, l2b, out);
}